// Round 15
// baseline (267.279 us; speedup 1.0000x reference)
//
#include <hip/hip_runtime.h>

#define LOG2E 1.4426950408889634f
#define LN2   0.6931471805599453f

typedef float f32x2 __attribute__((ext_vector_type(2)));

// r11 verified base (98 us, absmax 0): linear-domain fwd/bwd split,
//   alpha_t = D_t M alpha_{t-1},  beta_{t-1} = M^T (d_t beta_t),
// one wave per chain, LDS uniform-address ds_read_b128 broadcast,
// v_pk_fma_f32 matvec, immediate integer-exponent rescale every 2 steps,
// join Z = beta_m^T alpha_m at the midpoint.
//
// Round-15 change: software-pipeline the READS against the FMAs inside the
// step. Evidence (r7->r11 delta ~= full VALU-issue delta; r14 read-halving
// null): the compiler emits {16 ds_read_b128} -> lgkmcnt(0) -> {all FMAs},
// so the step pays stream (~192) PLUS FMA issue (~174) serially. A 4-deep
// rotating register pipeline (qa..qd) forces each FMA group to be followed
// by the refill load 4 groups ahead: loads stay >=4 in flight, FMAs trail
// the arriving data, and the step approaches max(stream, VALU) instead of
// their sum. Pure read reordering of an unchanging buffer — no numerics
// change, no cross-wave sync, no inline-asm scheduling.
template <bool FWD>
__device__ __forceinline__ void run_chain(
    const float* __restrict__ hb, const float* __restrict__ trans,
    float* __restrict__ pbuf, int lane, int len, int nsteps, int& b2Out) {
  constexpr int N = 64;

  // M fragment as 32 packed pairs: FWD lane i holds row i of M=exp(trans);
  // BWD lane j holds column j (row j of M^T). Prologue-only, L2-resident.
  f32x2 Mp[N / 2];
  if (FWD) {
    const float4* trow = (const float4*)(trans + lane * N);
#pragma unroll
    for (int q = 0; q < 16; ++q) {
      float4 tq = trow[q];
      Mp[2 * q + 0] = {__builtin_amdgcn_exp2f(tq.x * LOG2E),
                       __builtin_amdgcn_exp2f(tq.y * LOG2E)};
      Mp[2 * q + 1] = {__builtin_amdgcn_exp2f(tq.z * LOG2E),
                       __builtin_amdgcn_exp2f(tq.w * LOG2E)};
    }
  } else {
#pragma unroll
    for (int q = 0; q < 32; ++q) {
      Mp[q] = {__builtin_amdgcn_exp2f(trans[(2 * q + 0) * N + lane] * LOG2E),
               __builtin_amdgcn_exp2f(trans[(2 * q + 1) * N + lane] * LOG2E)};
    }
  }
  // Pin into arch VGPR pairs (r2/r9/r12: backend otherwise parks arrays in
  // AGPRs or scratch; VGPR_Count in counters is the tripwire).
#pragma unroll
  for (int q = 0; q < 8; ++q) {
    asm volatile("" : "+v"(Mp[4 * q + 0]), "+v"(Mp[4 * q + 1]),
                      "+v"(Mp[4 * q + 2]), "+v"(Mp[4 * q + 3]));
  }

  // Init state in LDS. FWD: alpha_0[i] = exp(h[0,i]+trans[i,START]).
  // BWD: u_END[i] = exp(trans[END,i]), folding d_{len-1} when there is at
  // least one matvec (write-folded scheme). START=N-2, END=N-1.
  {
    float v;
    if (FWD) {
      v = __builtin_amdgcn_exp2f((hb[lane] + trans[lane * N + (N - 2)]) * LOG2E);
    } else {
      v = __builtin_amdgcn_exp2f(trans[(N - 1) * N + lane] * LOG2E);
      if (nsteps >= 1)
        v *= __builtin_amdgcn_exp2f(hb[(size_t)(len - 1) * N + lane] * LOG2E);
    }
    pbuf[lane] = v;
  }
  int base2 = 0;

  // Folded-step count: FWD runs all nsteps with D applied after the matvec;
  // BWD runs nsteps-1 folded + one final RAW step (beta_m excludes d_m).
  const int ns = FWD ? nsteps : nsteps - 1;

  auto step = [&](float D, bool resc) {
    const float4* pb4 = (const float4*)pbuf;
    // 4-deep rotating read pipeline: load groups 0..3, then each FMA group
    // immediately issues the refill 4 groups ahead.
    float4 qa = pb4[0], qb = pb4[1], qc = pb4[2], qd = pb4[3];
    float mult = D;
    if (resc) {  // anchor = replicated p[0] of the consumed state (qa.x)
      unsigned bits = __float_as_uint(qa.x);
      int e = (int)((bits >> 23) & 0xffu);
      base2 += e - 127;
      mult *= __uint_as_float((unsigned)(254 - e) << 23);  // 2^(127-e)
    }
    f32x2 a0 = {0.f, 0.f}, a1 = {0.f, 0.f}, a2 = {0.f, 0.f}, a3 = {0.f, 0.f};
#define FMA_G(QV, G)                                                      \
    do {                                                                  \
      f32x2 qlo_ = {(QV).x, (QV).y}, qhi_ = {(QV).z, (QV).w};             \
      if (((G) & 1) == 0) {                                               \
        a0 = __builtin_elementwise_fma(Mp[2 * (G) + 0], qlo_, a0);        \
        a1 = __builtin_elementwise_fma(Mp[2 * (G) + 1], qhi_, a1);        \
      } else {                                                            \
        a2 = __builtin_elementwise_fma(Mp[2 * (G) + 0], qlo_, a2);        \
        a3 = __builtin_elementwise_fma(Mp[2 * (G) + 1], qhi_, a3);        \
      }                                                                   \
    } while (0)
    FMA_G(qa, 0);  qa = pb4[4];
    FMA_G(qb, 1);  qb = pb4[5];
    FMA_G(qc, 2);  qc = pb4[6];
    FMA_G(qd, 3);  qd = pb4[7];
    FMA_G(qa, 4);  qa = pb4[8];
    FMA_G(qb, 5);  qb = pb4[9];
    FMA_G(qc, 6);  qc = pb4[10];
    FMA_G(qd, 7);  qd = pb4[11];
    FMA_G(qa, 8);  qa = pb4[12];
    FMA_G(qb, 9);  qb = pb4[13];
    FMA_G(qc, 10); qc = pb4[14];
    FMA_G(qd, 11); qd = pb4[15];
    FMA_G(qa, 12);
    FMA_G(qb, 13);
    FMA_G(qc, 14);
    FMA_G(qd, 15);
#undef FMA_G
    f32x2 s01 = a0 + a1, s23 = a2 + a3;  // v_pk_add_f32
    f32x2 s2 = s01 + s23;
    pbuf[lane] = (s2.x + s2.y) * mult;  // per-lane write, 2-way alias = free
  };

  // Emission for folded step s: FWD t = s; BWD t = len-1-s (write-fold).
  auto emit_of = [&](int s_) -> float {
    int smax = ns < 1 ? 1 : ns;
    int sc = s_ < smax ? s_ : smax;
    if (sc < 1) sc = 1;
    int t = FWD ? sc : (len - 1 - sc);
    if (t < 0) t = 0;  // value unused in these cases; keep address in range
    return __builtin_amdgcn_exp2f(hb[(size_t)t * N + lane] * LOG2E);
  };

  float eb[8];
#pragma unroll
  for (int u = 0; u < 8; ++u) eb[u] = emit_of(1 + u);

  int s = 1;
  for (; s + 8 <= ns + 1; s += 8) {
#pragma unroll
    for (int u = 0; u < 8; ++u) {
      step(eb[u], (u & 1) == 1);  // rescale every 2 steps
      eb[u] = emit_of(s + u + 8);
    }
  }
  for (; s <= ns; ++s) {  // tail; slot for step s is (s-1)&7
    step(eb[(s - 1) & 7], true);
  }
  if (!FWD && nsteps >= 1) step(1.0f, true);  // final raw beta_m step

  b2Out = base2;
}

__global__ __launch_bounds__(128)
__attribute__((amdgpu_waves_per_eu(1, 1)))
void crf_fwd_33852932227637(
    const float* __restrict__ h,
    const float* __restrict__ trans,
    const int* __restrict__ lengths,
    float* __restrict__ out,
    int T) {
  constexpr int N = 64;
  const int b = blockIdx.x;
  const int lane = threadIdx.x & 63;
  const int wv = threadIdx.x >> 6;

  const float* hb = h + (size_t)b * T * N;
  const int len = lengths[b];
  const int m = (len - 1) >> 1;  // fwd matvecs: 1..m ; bwd matvecs: len-1..m+1

  __shared__ __align__(16) float pbuf[2][N];
  __shared__ int xb2[2];

  int b2;
  if (wv == 0)
    run_chain<true>(hb, trans, pbuf[0], lane, len, m, b2);
  else
    run_chain<false>(hb, trans, pbuf[1], lane, len, len - 1 - m, b2);
  if (lane == 0) xb2[wv] = b2;
  __syncthreads();

  if (wv == 0) {
    // Z * 2^-(b2f+b2b) = sum_i alpha_m[i] * beta_m[i]; anchors keep both
    // factors ~2^0, so the dot neither over- nor underflows.
    float z = pbuf[0][lane] * pbuf[1][lane];
#pragma unroll
    for (int off = 32; off >= 1; off >>= 1)
      z += __shfl_xor(z, off, 64);
    if (lane == 0)
      out[b] = LN2 * ((float)(xb2[0] + xb2[1]) + __builtin_amdgcn_logf(z));
  }
}

extern "C" void kernel_launch(void* const* d_in, const int* in_sizes, int n_in,
                              void* d_out, int out_size, void* d_ws, size_t ws_size,
                              hipStream_t stream) {
  const float* h = (const float*)d_in[0];
  const float* trans = (const float*)d_in[1];
  const int* lengths = (const int*)d_in[2];
  float* out = (float*)d_out;
  const int B = in_sizes[2];
  const int N = 64;
  const int T = in_sizes[0] / (B * N);
  crf_fwd_33852932227637<<<B, N * 2, 0, stream>>>(h, trans, lengths, out, T);
}